// Round 2
// baseline (210.975 us; speedup 1.0000x reference)
//
#include <hip/hip_runtime.h>

#define NCLS 256
#define NSMP 32
#define DIM  2048
#define DV   (DIM / 4)          // 512 float4 columns per sample
#define BLK  512                // one thread per float4 column
#define NWAVE (BLK / 64)        // 8 waves

__global__ __launch_bounds__(BLK, 2)
void ccl_kernel(const float* __restrict__ emb,
                const float* __restrict__ margin_p,
                float* __restrict__ out) {
    const int c    = blockIdx.x;
    const int tid  = threadIdx.x;
    const int wave = tid >> 6;
    const int lane = tid & 63;

    __shared__ float pp[NWAVE][NSMP];   // per-wave pos partial d^2
    __shared__ float pn[NWAVE][NSMP];   // per-wave neg partial d^2

    const float4* pos = (const float4*)(emb + (size_t)c * 2 * NSMP * DIM);
    const float4* neg = pos + (size_t)NSMP * DV;

    // ---- load all 32 pos samples of this thread's column into registers
    float4 x[NSMP];
    #pragma unroll
    for (int i = 0; i < NSMP; ++i) x[i] = pos[(size_t)i * DV + tid];

    // ---- anchor (this column) = mean over samples, fully in-register
    float4 a = make_float4(0.f, 0.f, 0.f, 0.f);
    #pragma unroll
    for (int i = 0; i < NSMP; ++i) {
        a.x += x[i].x; a.y += x[i].y; a.z += x[i].z; a.w += x[i].w;
    }
    const float inv = 1.0f / (float)NSMP;
    a.x *= inv; a.y *= inv; a.z *= inv; a.w *= inv;

    // ---- pos d^2 partials per sample (from registers, no re-read)
    #pragma unroll
    for (int i = 0; i < NSMP; ++i) {
        float dx = x[i].x - a.x, dy = x[i].y - a.y;
        float dz = x[i].z - a.z, dw = x[i].w - a.w;
        float p  = dx * dx + dy * dy + dz * dz + dw * dw;
        #pragma unroll
        for (int off = 32; off >= 1; off >>= 1) p += __shfl_xor(p, off, 64);
        if (lane == 0) pp[wave][i] = p;
    }

    // ---- neg d^2 partials per sample (streamed once)
    #pragma unroll
    for (int i = 0; i < NSMP; ++i) {
        float4 n = neg[(size_t)i * DV + tid];
        float dx = n.x - a.x, dy = n.y - a.y;
        float dz = n.z - a.z, dw = n.w - a.w;
        float p  = dx * dx + dy * dy + dz * dz + dw * dw;
        #pragma unroll
        for (int off = 32; off >= 1; off >>= 1) p += __shfl_xor(p, off, 64);
        if (lane == 0) pn[wave][i] = p;
    }
    __syncthreads();

    // ---- finalize on wave 0: lane s (<32) owns sample s
    if (wave == 0) {
        float d2p = 0.f, d2n = 0.f;
        if (lane < NSMP) {
            #pragma unroll
            for (int w = 0; w < NWAVE; ++w) { d2p += pp[w][lane]; d2n += pn[w][lane]; }
        } else {
            d2n = 3.4e38f;
        }

        // an = sqrt(min over samples of neg d^2), broadcast to all lanes
        float nd = d2n;
        #pragma unroll
        for (int off = 32; off >= 1; off >>= 1) nd = fminf(nd, __shfl_xor(nd, off, 64));
        const float an = sqrtf(nd);
        const float margin = margin_p[0];

        float l = 0.f;
        if (lane < NSMP) {
            float ap = sqrtf(d2p);
            float v  = fmaxf(ap - an + margin, 0.f);
            l = v * v;
        }
        #pragma unroll
        for (int off = 32; off >= 1; off >>= 1) l += __shfl_xor(l, off, 64);
        if (lane == 0) atomicAdd(out, l * (1.0f / (float)NCLS));
    }
}

extern "C" void kernel_launch(void* const* d_in, const int* in_sizes, int n_in,
                              void* d_out, int out_size, void* d_ws, size_t ws_size,
                              hipStream_t stream) {
    const float* emb    = (const float*)d_in[0];
    // d_in[1] = target (unused by the reference)
    const float* margin = (const float*)d_in[2];
    float* out = (float*)d_out;

    hipMemsetAsync(out, 0, sizeof(float), stream);
    ccl_kernel<<<NCLS, BLK, 0, stream>>>(emb, margin, out);
}

// Round 3
// 197.307 us; speedup vs baseline: 1.0693x; 1.0693x over previous
//
#include <hip/hip_runtime.h>

#define NCLS 256
#define NSMP 32
#define DIM  2048
#define DV   (DIM / 4)      // 512 float4 columns per sample
#define BLK  512            // one thread per float4 column
#define ROWS 520            // padded LDS row stride (floats): conflict-minimal transpose reads
#define PF   8              // neg prefetch depth

__global__ __launch_bounds__(BLK, 2)
void ccl_kernel(const float* __restrict__ emb,
                const float* __restrict__ margin_p,
                float* __restrict__ out) {
    const int c   = blockIdx.x;
    const int tid = threadIdx.x;

    __shared__ float part[NSMP * ROWS];   // 65 KB, reused for pos then neg
    __shared__ float d2p[NSMP];
    __shared__ float d2n[NSMP];

    const float4* pos = (const float4*)(emb + (size_t)c * 2 * NSMP * DIM);
    const float4* neg = pos + (size_t)NSMP * DV;

    // ---- load all 32 pos samples of this thread's column into registers
    float4 x[NSMP];
    #pragma unroll
    for (int i = 0; i < NSMP; ++i) x[i] = pos[(size_t)i * DV + tid];

    // ---- anchor (this column) = mean over samples, in-register
    float4 a = make_float4(0.f, 0.f, 0.f, 0.f);
    #pragma unroll
    for (int i = 0; i < NSMP; ++i) {
        a.x += x[i].x; a.y += x[i].y; a.z += x[i].z; a.w += x[i].w;
    }
    const float inv = 1.0f / (float)NSMP;
    a.x *= inv; a.y *= inv; a.z *= inv; a.w *= inv;

    // ---- prefetch first PF neg samples (keeps HBM busy through reduce phases)
    float4 nb[PF];
    #pragma unroll
    for (int j = 0; j < PF; ++j) nb[j] = neg[(size_t)j * DV + tid];

    // ---- pos d^2 partials -> LDS (consecutive lanes, conflict-free writes)
    #pragma unroll
    for (int i = 0; i < NSMP; ++i) {
        float dx = x[i].x - a.x, dy = x[i].y - a.y;
        float dz = x[i].z - a.z, dw = x[i].w - a.w;
        part[i * ROWS + tid] = dx * dx + dy * dy + dz * dz + dw * dw;
    }
    __syncthreads();

    // ---- transpose-reduce pos: 16 threads per sample
    const int s   = tid >> 4;   // sample owned by this thread group
    const int c16 = tid & 15;   // chunk id within the sample
    {
        float sum = 0.f;
        #pragma unroll
        for (int k = 0; k < 8; ++k) {
            float4 v = *(const float4*)&part[s * ROWS + c16 * 4 + k * 64];
            sum += v.x + v.y + v.z + v.w;
        }
        #pragma unroll
        for (int off = 8; off >= 1; off >>= 1) sum += __shfl_xor(sum, off, 64);
        if (c16 == 0) d2p[s] = sum;
    }
    __syncthreads();   // part[] about to be overwritten by neg partials

    // ---- neg d^2 partials with rolling prefetch
    #pragma unroll
    for (int i = 0; i < NSMP; ++i) {
        float4 n = nb[i & (PF - 1)];
        if (i + PF < NSMP) nb[i & (PF - 1)] = neg[(size_t)(i + PF) * DV + tid];
        float dx = n.x - a.x, dy = n.y - a.y;
        float dz = n.z - a.z, dw = n.w - a.w;
        part[i * ROWS + tid] = dx * dx + dy * dy + dz * dz + dw * dw;
    }
    __syncthreads();

    // ---- transpose-reduce neg
    {
        float sum = 0.f;
        #pragma unroll
        for (int k = 0; k < 8; ++k) {
            float4 v = *(const float4*)&part[s * ROWS + c16 * 4 + k * 64];
            sum += v.x + v.y + v.z + v.w;
        }
        #pragma unroll
        for (int off = 8; off >= 1; off >>= 1) sum += __shfl_xor(sum, off, 64);
        if (c16 == 0) d2n[s] = sum;
    }
    __syncthreads();

    // ---- finalize on wave 0: lane s (<32) owns sample s
    if (tid < 64) {
        float nd = (tid < NSMP) ? d2n[tid] : 3.4e38f;
        #pragma unroll
        for (int off = 32; off >= 1; off >>= 1) nd = fminf(nd, __shfl_xor(nd, off, 64));
        const float an = sqrtf(nd);
        const float margin = margin_p[0];

        float l = 0.f;
        if (tid < NSMP) {
            float ap = sqrtf(d2p[tid]);
            float v  = fmaxf(ap - an + margin, 0.f);
            l = v * v;
        }
        #pragma unroll
        for (int off = 32; off >= 1; off >>= 1) l += __shfl_xor(l, off, 64);
        if (tid == 0) atomicAdd(out, l * (1.0f / (float)NCLS));
    }
}

extern "C" void kernel_launch(void* const* d_in, const int* in_sizes, int n_in,
                              void* d_out, int out_size, void* d_ws, size_t ws_size,
                              hipStream_t stream) {
    const float* emb    = (const float*)d_in[0];
    // d_in[1] = target (unused by the reference)
    const float* margin = (const float*)d_in[2];
    float* out = (float*)d_out;

    hipMemsetAsync(out, 0, sizeof(float), stream);
    ccl_kernel<<<NCLS, BLK, 0, stream>>>(emb, margin, out);
}